// Round 5
// baseline (304.057 us; speedup 1.0000x reference)
//
#include <hip/hip_runtime.h>
#include <stdint.h>

typedef unsigned short u16;
typedef __bf16 bf16x8 __attribute__((ext_vector_type(8)));
typedef float f32x4 __attribute__((ext_vector_type(4)));

#define DEVINL __device__ __forceinline__

DEVINL u16 f2bf(float f){
  uint32_t x = __float_as_uint(f);
  uint32_t r = (x + 0x7fffu + ((x >> 16) & 1u)) >> 16;
  return (u16)r;
}

DEVINL float wave_sum(float v){
#pragma unroll
  for (int off = 32; off; off >>= 1) v += __shfl_xor(v, off);
  return v;
}

DEVINL float dot8(float4 a0, float4 a1, float4 b0, float4 b1){
  return a0.x*b0.x + a0.y*b0.y + a0.z*b0.z + a0.w*b0.w
       + a1.x*b1.x + a1.y*b1.y + a1.z*b1.z + a1.w*b1.w;
}

DEVINL void gload_lds16(const void* g, void* l){
  __builtin_amdgcn_global_load_lds(
      (const __attribute__((address_space(1))) uint32_t*)g,
      (__attribute__((address_space(3))) uint32_t*)l, 16, 0, 0);
}

// ---------------- fused: cf = relu(Wp @ pf + bp)  +  wconv + flag init ------
__global__ __launch_bounds__(256) void cfw_kernel(
    const float* __restrict__ Wp, const float* __restrict__ pf,
    const float* __restrict__ bp, const float* __restrict__ Wop,
    float* __restrict__ feats, u16* __restrict__ wfb, int* __restrict__ flag)
{
  const int bid = blockIdx.x, tid = threadIdx.x;
  if (bid == 0 && tid == 0) *flag = 0;
  if (bid < 16384){
    const int lane = tid & 63, wid = tid >> 6;
    const int n = (bid << 2) + wid;                 // 0..65535
    const float4* row = (const float4*)(Wp + (size_t)n * 512);
    const float4* p   = (const float4*)pf;
    float4 w0 = row[lane*2], w1 = row[lane*2+1];
    float4 p0 = p[lane*2],  p1 = p[lane*2+1];
    float v = wave_sum(dot8(w0, w1, p0, p1));
    if (lane == 0){
      float r = fmaxf(v + bp[n], 0.f);
      feats[(size_t)(n >> 9) * 1536 + (n & 511)] = r;
    }
  } else {
    const int t = (bid - 16384) * 256 + tid;        // 0..65535
    const int e = t * 8;                            // elem in [2][512][512]
    const int it = e >> 18;
    const int rem = e & 262143;
    const int h = rem >> 9, k = rem & 511;
    const float* src = Wop + (size_t)it*788480 + (size_t)h*1540 + 1024 + k;
    float4 v0 = ((const float4*)src)[0];
    float4 v1 = ((const float4*)src)[1];
    union { u16 u[8]; uint4 q4; } o;
    o.u[0]=f2bf(v0.x); o.u[1]=f2bf(v0.y); o.u[2]=f2bf(v0.z); o.u[3]=f2bf(v0.w);
    o.u[4]=f2bf(v1.x); o.u[5]=f2bf(v1.y); o.u[6]=f2bf(v1.z); o.u[7]=f2bf(v1.w);
    *(uint4*)(wfb + e) = o.q4;
  }
}

// ---------------- W-stationary dot GEMM (K=512): 4 n-cols/wave, loop M ------
// Weight frags hoisted in regs -> each weight row read once per y-split.
DEVINL void gemm_w512(const float* __restrict__ A, int lda,
                      const float* __restrict__ W, int ldw,
                      const float* __restrict__ bias,
                      float* __restrict__ C, int ldc,
                      int m0, int mrows, int n0, int nmax, bool relu, int lane)
{
  float4 w[2][4];
#pragma unroll
  for (int q = 0; q < 4; q++){
    int n = n0 + q; if (n >= nmax) n = nmax - 1;
    const float* wr = W + (size_t)n * ldw + lane * 4;
    w[0][q] = *(const float4*)(wr);
    w[1][q] = *(const float4*)(wr + 256);
  }
  for (int mc = 0; mc < mrows; mc += 8){
    float acc[8][4] = {};
#pragma unroll
    for (int kc = 0; kc < 2; kc++){
#pragma unroll
      for (int r = 0; r < 8; r++){
        float4 a4 = *(const float4*)(A + (size_t)(m0 + mc + r) * lda + kc*256 + lane*4);
#pragma unroll
        for (int q = 0; q < 4; q++)
          acc[r][q] = fmaf(w[kc][q].x, a4.x, fmaf(w[kc][q].y, a4.y,
                      fmaf(w[kc][q].z, a4.z, fmaf(w[kc][q].w, a4.w, acc[r][q]))));
      }
    }
#pragma unroll
    for (int r = 0; r < 8; r++){
#pragma unroll
      for (int q = 0; q < 4; q++){
        float v = wave_sum(acc[r][q]);
        const int n = n0 + q;
        if (lane == 0 && n < nmax){
          float o = v + (bias ? bias[n] : 0.f);
          if (relu) o = fmaxf(o, 0.f);
          C[(size_t)(m0 + mc + r) * ldc + n] = o;
        }
      }
    }
  }
}

// ---------------- P/Q + it0 A/B (4 slabs) + exists; grid (129, 2) -----------
__global__ __launch_bounds__(256) void gemmPQAB(
    const float* __restrict__ feats,
    const float* __restrict__ Wel, const float* __restrict__ bel,
    const float* __restrict__ Wop, const float* __restrict__ bop,
    const float* __restrict__ We,  const float* __restrict__ be,
    float* __restrict__ P, float* __restrict__ Q,
    float* __restrict__ wsA, float* __restrict__ wsB,
    float* __restrict__ out_ex, float* __restrict__ exw)
{
  const int lane = threadIdx.x & 63, wid = threadIdx.x >> 6;
  const int bx = blockIdx.x, m0 = blockIdx.y * 64;
  if (bx < 128){
    const int n0 = (bx*4 + wid)*4;
    const int slab = n0 >> 9, nl = n0 & 511;
    const float* W; int ldw; const float* bias; float* C;
    switch (slab){
      case 0:  W = Wel;       ldw = 1024; bias = bel; C = P;   break;
      case 1:  W = Wel + 512; ldw = 1024; bias = 0;   C = Q;   break;
      case 2:  W = Wop;       ldw = 1540; bias = bop; C = wsA; break;
      default: W = Wop + 512; ldw = 1540; bias = 0;   C = wsB; break;
    }
    gemm_w512(feats, 1536, W, ldw, bias, C, 512, m0, 64, nl, 512, false, lane);
  } else {
    const float4* w = (const float4*)We;
    float4 w0 = w[lane*2], w1 = w[lane*2+1];
#pragma unroll
    for (int r = 0; r < 16; r++){
      const int m = m0 + wid*16 + r;
      const float4* a = (const float4*)(feats + (size_t)m*1536);
      float v = wave_sum(dot8(a[lane*2], a[lane*2+1], w0, w1));
      if (lane == 0){ float o = v + be[0]; out_ex[m] = o; exw[m] = o; }
    }
  }
}

// ---------------- it1 A/B gemm (2 slabs); grid (64, 2) ----------------------
__global__ __launch_bounds__(256) void gemmAB1(
    const float* __restrict__ feats,
    const float* __restrict__ Wop1, const float* __restrict__ bop1,
    float* __restrict__ wsA, float* __restrict__ wsB)
{
  const int lane = threadIdx.x & 63, wid = threadIdx.x >> 6;
  const int bx = blockIdx.x, m0 = blockIdx.y * 64;
  const int n0 = (bx*4 + wid)*4;
  const int slab = n0 >> 9, nl = n0 & 511;
  const float* W   = slab ? (Wop1 + 512) : Wop1;
  const float* bias= slab ? 0 : bop1;
  float* C         = slab ? wsB : wsA;
  gemm_w512(feats + 512, 1536, W, 1540, bias, C, 512, m0, 64, nl, 512, false, lane);
}

// ---------------- head: h = relu(feats @ Wc.T + bc), K=1536; grid (64, 2) ---
__global__ __launch_bounds__(256) void head_kernel(
    const float* __restrict__ feats, const float* __restrict__ Wc,
    const float* __restrict__ bc, float* __restrict__ wsH)
{
  const int lane = threadIdx.x & 63, wid = threadIdx.x >> 6;
  const int n0 = (blockIdx.x*4 + wid)*2;
  const int m0 = blockIdx.y * 64;
  float4 w[6][2];
#pragma unroll
  for (int q = 0; q < 2; q++){
    const float* wr = Wc + (size_t)(n0 + q) * 1536 + lane * 4;
#pragma unroll
    for (int kc = 0; kc < 6; kc++) w[kc][q] = *(const float4*)(wr + kc*256);
  }
  for (int mc = 0; mc < 64; mc += 8){
    float acc[8][2] = {};
#pragma unroll
    for (int kc = 0; kc < 6; kc++){
#pragma unroll
      for (int r = 0; r < 8; r++){
        float4 a4 = *(const float4*)(feats + (size_t)(m0 + mc + r)*1536 + kc*256 + lane*4);
#pragma unroll
        for (int q = 0; q < 2; q++)
          acc[r][q] = fmaf(w[kc][q].x, a4.x, fmaf(w[kc][q].y, a4.y,
                      fmaf(w[kc][q].z, a4.z, fmaf(w[kc][q].w, a4.w, acc[r][q]))));
      }
    }
#pragma unroll
    for (int r = 0; r < 8; r++){
#pragma unroll
      for (int q = 0; q < 2; q++){
        float v = wave_sum(acc[r][q]);
        if (lane == 0)
          wsH[(size_t)(m0 + mc + r)*512 + n0 + q] = fmaxf(v + bc[n0 + q], 0.f);
      }
    }
  }
}

// ---------------- el (bf16) + eel (f32) + has_edges; one wave per (i,j) ------
__global__ __launch_bounds__(256) void el_kernel(
    const float* __restrict__ P, const float* __restrict__ Q,
    const float* __restrict__ Wee, const float* __restrict__ bee,
    const float* __restrict__ ex,
    u16* __restrict__ elb, float* __restrict__ eelOut, int* __restrict__ flag)
{
  const int lane = threadIdx.x & 63, wid = threadIdx.x >> 6;
  const int row = (blockIdx.x << 2) + wid;          // 0..16383
  const int i = row >> 7, j = row & 127;
  const int k0 = lane << 3;
  float4 p0 = *(const float4*)(P + (size_t)i*512 + k0);
  float4 p1 = *(const float4*)(P + (size_t)i*512 + k0 + 4);
  float4 q0 = *(const float4*)(Q + (size_t)j*512 + k0);
  float4 q1 = *(const float4*)(Q + (size_t)j*512 + k0 + 4);
  float e[8];
  e[0]=fmaxf(p0.x+q0.x,0.f); e[1]=fmaxf(p0.y+q0.y,0.f);
  e[2]=fmaxf(p0.z+q0.z,0.f); e[3]=fmaxf(p0.w+q0.w,0.f);
  e[4]=fmaxf(p1.x+q1.x,0.f); e[5]=fmaxf(p1.y+q1.y,0.f);
  e[6]=fmaxf(p1.z+q1.z,0.f); e[7]=fmaxf(p1.w+q1.w,0.f);
  union { u16 u[8]; uint4 q4; } o;
#pragma unroll
  for (int c = 0; c < 8; c++) o.u[c] = f2bf(e[c]);
  *(uint4*)(elb + (size_t)row*512 + k0) = o.q4;
  float acc[4];
#pragma unroll
  for (int t = 0; t < 4; t++){
    float4 w0 = *(const float4*)(Wee + t*512 + k0);
    float4 w1 = *(const float4*)(Wee + t*512 + k0 + 4);
    acc[t] = wave_sum(e[0]*w0.x + e[1]*w0.y + e[2]*w0.z + e[3]*w0.w
                    + e[4]*w1.x + e[5]*w1.y + e[6]*w1.z + e[7]*w1.w);
  }
  bool wf = false;
  if (lane == 0){
    float4 r = make_float4(acc[0]+bee[0], acc[1]+bee[1], acc[2]+bee[2], acc[3]+bee[3]);
    *(float4*)(eelOut + (size_t)row*4) = r;
    wf = (ex[i] > 0.f) && (ex[j] > 0.f) &&
         (r.x > 0.f || r.y > 0.f || r.z > 0.f || r.w > 0.f);
  }
  // flag: ballot + load-guard -> at most a handful of actual atomics
  if (__ballot(wf)){
    if (lane == 0 &&
        __hip_atomic_load(flag, __ATOMIC_RELAXED, __HIP_MEMORY_SCOPE_AGENT) == 0)
      atomicOr(flag, 1);
  }
}

// ---------------- fused E-GEMM + msg + masked max per iteration -------------
// 1024 blocks: tile 128j x 64h, BK=64, dbuf, counted vmcnt(6) pipeline.
// XCD map: bid&7 = xcd; each XCD owns 16 i-panels x 8 h-tiles (L2 reuse).
__global__ __launch_bounds__(256, 3) void iter_kernel(
    const u16* __restrict__ el, const u16* __restrict__ wfb,
    const float* __restrict__ Aterm, const float* __restrict__ Bterm,
    const float* __restrict__ eel, const float* __restrict__ ex,
    const float* __restrict__ wopWt,      // Wop + it*788480 (Wt cols 1536..)
    const int* __restrict__ flag,
    float* __restrict__ feats, int it)
{
  __shared__ u16 tile[2][12288];    // per buf: A 128x64 bf16 (16KB) + B 64x64 (8KB)
  __shared__ float smax[4][64];
  const int tid = threadIdx.x;
  const int lane = tid & 63, wid = tid >> 6;
  const int bid = blockIdx.x;
  const int xcd = bid & 7, loc = bid >> 3;
  const int i   = xcd*16 + (loc & 15);
  const int hc0 = (loc >> 4) << 6;

  // staging: 6 chunks/thread/step (A:4, B:2), 16B each; LDS linear,
  // global col-slot pre-swizzled: cb = s ^ (r&7)  (8 slots of 16B per 128B row).
  const u16* src[6]; int dst[6];
#pragma unroll
  for (int rd = 0; rd < 6; rd++){
    int c = tid + 256*rd;
    if (c < 1024){
      int r = c >> 3, s = c & 7, cb = s ^ (r & 7);
      src[rd] = el + (size_t)(i*128 + r)*512 + (cb << 3);
      dst[rd] = c << 3;
    } else {
      int c2 = c - 1024;
      int r = c2 >> 3, s = c2 & 7, cb = s ^ (r & 7);
      src[rd] = wfb + (size_t)(hc0 + r)*512 + (cb << 3);
      dst[rd] = 8192 + (c2 << 3);
    }
  }

  const int slog = lane >> 4;
  int byteA[2][2], byteB[2][4];
#pragma unroll
  for (int k2 = 0; k2 < 2; k2++){
#pragma unroll
    for (int fa = 0; fa < 2; fa++){
      int ra = wid*32 + fa*16 + (lane & 15);
      byteA[k2][fa] = ra*128 + (((k2*4 + slog) ^ (ra & 7)) << 4);
    }
#pragma unroll
    for (int f = 0; f < 4; f++){
      int rb = f*16 + (lane & 15);
      byteB[k2][f] = 16384 + rb*128 + (((k2*4 + slog) ^ (rb & 7)) << 4);
    }
  }

  f32x4 acc[2][4] = {};

  auto stage = [&](int buf, int ks){
    const int k0 = ks << 6;
#pragma unroll
    for (int rd = 0; rd < 6; rd++)
      gload_lds16(src[rd] + k0, &tile[buf][dst[rd]]);
  };

  // counted-vmcnt double-buffer pipeline: batch k+2 in flight during compute k
  stage(0, 0);
  stage(1, 1);
  asm volatile("s_waitcnt vmcnt(6)" ::: "memory");   // batch0 landed
  __builtin_amdgcn_s_barrier();
  __builtin_amdgcn_sched_barrier(0);
#pragma unroll
  for (int ks = 0; ks < 8; ks++){
    const int cur = ks & 1;
    const char* base = (const char*)&tile[cur][0];
#pragma unroll
    for (int k2 = 0; k2 < 2; k2++){
      bf16x8 a[2], b[4];
#pragma unroll
      for (int fa = 0; fa < 2; fa++) a[fa] = *(const bf16x8*)(base + byteA[k2][fa]);
#pragma unroll
      for (int f = 0; f < 4; f++)   b[f]  = *(const bf16x8*)(base + byteB[k2][f]);
#pragma unroll
      for (int fa = 0; fa < 2; fa++)
#pragma unroll
        for (int f = 0; f < 4; f++)
          acc[fa][f] = __builtin_amdgcn_mfma_f32_16x16x32_bf16(a[fa], b[f], acc[fa][f], 0, 0, 0);
    }
    __builtin_amdgcn_s_barrier();      // all waves done reading tile[cur]
    __builtin_amdgcn_sched_barrier(0);
    if (ks < 6){
      stage(cur, ks + 2);              // overwrite cur with batch ks+2
      asm volatile("s_waitcnt vmcnt(6)" ::: "memory");  // batch ks+1 landed
    } else {
      asm volatile("s_waitcnt vmcnt(0)" ::: "memory");  // tail drain
    }
    __builtin_amdgcn_s_barrier();
    __builtin_amdgcn_sched_barrier(0);
  }

  // epilogue: msg = relu(pre + e0*Wt), masked max over (j,t)
  const bool mi = ex[i] > 0.f;
  float Ah[4]; float4 wt[4]; int hg[4];
#pragma unroll
  for (int f = 0; f < 4; f++){
    hg[f] = hc0 + f*16 + (lane & 15);
    Ah[f] = Aterm[i*512 + hg[f]];
    wt[f] = *(const float4*)(wopWt + (size_t)hg[f]*1540 + 1536);
  }
  float tm[4] = {0.f, 0.f, 0.f, 0.f};
#pragma unroll
  for (int fa = 0; fa < 2; fa++){
    const int j0 = wid*32 + fa*16 + slog*4;
#pragma unroll
    for (int r = 0; r < 4; r++){
      const int j = j0 + r;
      float4 e4 = *(const float4*)(eel + (size_t)(i*128 + j)*4);
      const bool mj = mi && (ex[j] > 0.f);
      const bool c0 = mj && (e4.x > 0.f), c1 = mj && (e4.y > 0.f);
      const bool c2 = mj && (e4.z > 0.f), c3 = mj && (e4.w > 0.f);
#pragma unroll
      for (int f = 0; f < 4; f++){
        float val = acc[fa][f][r] + Ah[f] + Bterm[(size_t)j*512 + hg[f]];
        if (c0) tm[f] = fmaxf(tm[f], val + e4.x*wt[f].x);
        if (c1) tm[f] = fmaxf(tm[f], val + e4.y*wt[f].y);
        if (c2) tm[f] = fmaxf(tm[f], val + e4.z*wt[f].z);
        if (c3) tm[f] = fmaxf(tm[f], val + e4.w*wt[f].w);
      }
    }
  }
#pragma unroll
  for (int f = 0; f < 4; f++){
    float v = tm[f];
    v = fmaxf(v, __shfl_xor(v, 16));
    v = fmaxf(v, __shfl_xor(v, 32));
    if (lane < 16) smax[wid][f*16 + lane] = v;
  }
  __syncthreads();
  if (tid < 64){
    const float v = fmaxf(fmaxf(smax[0][tid], smax[1][tid]),
                          fmaxf(smax[2][tid], smax[3][tid]));
    const int hgl = hc0 + tid;
    const float prev = feats[(size_t)i*1536 + it*512 + hgl];
    feats[(size_t)i*1536 + 512 + it*512 + hgl] = (*flag) ? v : prev;
  }
}

// ---------------- gemm4: dual slab, per-slab relu/ldc (sem + cf2) -----------
template<bool RA, bool RB>
__global__ __launch_bounds__(256) void gemm4(
    const float* __restrict__ A, int lda,
    const float* __restrict__ Wa, const float* __restrict__ Wb,
    int ldw, int Nsplit,
    const float* __restrict__ biasA, const float* __restrict__ biasB,
    float* __restrict__ Ca, float* __restrict__ Cb, int ldcA, int ldcB,
    int N, int K)
{
  const int lane = threadIdx.x & 63, wid = threadIdx.x >> 6;
  const int n0 = (blockIdx.x * 4 + wid) * 4;
  const int m0 = blockIdx.y * 8;
  const float* wrow[4];
#pragma unroll
  for (int q = 0; q < 4; q++){
    int n = n0 + q;
    int nn = n; const float* W = Wa;
    if (n >= Nsplit){ nn = n - Nsplit; W = Wb; }
    if (n >= N){ nn = 0; W = Wa; }
    wrow[q] = W + (size_t)nn * ldw + lane * 4;
  }
  const float* arow = A + (size_t)m0 * lda + lane * 4;
  float acc[8][4] = {};
  for (int kc = 0; kc < K; kc += 256){
    float4 w4[4];
#pragma unroll
    for (int q = 0; q < 4; q++) w4[q] = *(const float4*)(wrow[q] + kc);
#pragma unroll
    for (int r = 0; r < 8; r++){
      float4 a4 = *(const float4*)(arow + (size_t)r * lda + kc);
#pragma unroll
      for (int q = 0; q < 4; q++)
        acc[r][q] = fmaf(w4[q].x, a4.x, fmaf(w4[q].y, a4.y,
                    fmaf(w4[q].z, a4.z, fmaf(w4[q].w, a4.w, acc[r][q]))));
    }
  }
#pragma unroll
  for (int r = 0; r < 8; r++){
#pragma unroll
    for (int q = 0; q < 4; q++){
      float v = wave_sum(acc[r][q]);
      const int n = n0 + q;
      if (lane == 0 && n < N){
        const bool sb = n >= Nsplit;
        const float* bs = sb ? biasB : biasA;
        float o = v + (bs ? bs[sb ? n - Nsplit : n] : 0.f);
        if (sb ? RB : RA) o = fmaxf(o, 0.f);
        if (sb) Cb[(size_t)(m0 + r) * ldcB + (n - Nsplit)] = o;
        else    Ca[(size_t)(m0 + r) * ldcA + n] = o;
      }
    }
  }
}

// ---------------------------------------------------------------------------
extern "C" void kernel_launch(void* const* d_in, const int* in_sizes, int n_in,
                              void* d_out, int out_size, void* d_ws, size_t ws_size,
                              hipStream_t stream)
{
  const float* pf   = (const float*)d_in[0];
  const float* Wp   = (const float*)d_in[1];
  const float* bp   = (const float*)d_in[2];
  const float* We   = (const float*)d_in[3];
  const float* be   = (const float*)d_in[4];
  const float* Wsem = (const float*)d_in[5];
  const float* bsem = (const float*)d_in[6];
  const float* Wel  = (const float*)d_in[7];
  const float* bel  = (const float*)d_in[8];
  const float* Wee  = (const float*)d_in[9];
  const float* bee  = (const float*)d_in[10];
  const float* Wop  = (const float*)d_in[11];
  const float* bop  = (const float*)d_in[12];
  const float* Wc   = (const float*)d_in[13];
  const float* bc   = (const float*)d_in[14];
  const float* Wc2  = (const float*)d_in[15];
  const float* bc2  = (const float*)d_in[16];

  float* out      = (float*)d_out;
  float* out_cf   = out;             // [128,512]
  float* out_sem  = out + 65536;     // [128,50]
  float* out_ex   = out + 71936;     // [128]
  float* out_eel  = out + 72064;     // [128,128,4]

  char* ws = (char*)d_ws;
  u16*   elb   = (u16*)ws;                                // 16 MB bf16 el
  float* feats = (float*)(ws + 16777216);                 // [128][1536]
  float* P     = feats + 196608;                          // [128][512]
  float* Q     = P + 65536;
  float* wsA   = Q + 65536;
  float* wsB   = wsA + 65536;
  float* wsH   = wsB + 65536;
  float* exw   = wsH + 65536;                             // [128]
  int*   flag  = (int*)(exw + 160);
  u16*   wfb   = (u16*)(flag + 64);                       // [2][512][512] bf16

  cfw_kernel<<<16640, 256, 0, stream>>>(Wp, pf, bp, Wop, feats, wfb, flag);
  gemmPQAB<<<dim3(129, 2), 256, 0, stream>>>(feats, Wel, bel, Wop, bop, We, be,
                                             P, Q, wsA, wsB, out_ex, exw);
  el_kernel<<<4096, 256, 0, stream>>>(P, Q, Wee, bee, exw, elb, out_eel, flag);

  for (int it = 0; it < 2; it++){
    const float* Wit = Wop + (size_t)it * 788480;
    if (it == 1)
      gemmAB1<<<dim3(64, 2), 256, 0, stream>>>(feats, Wit, bop + 512, wsA, wsB);
    iter_kernel<<<1024, 256, 0, stream>>>(elb, wfb + it*262144, wsA, wsB,
                                          out_eel, exw, Wit, flag, feats, it);
  }
  head_kernel<<<dim3(64, 2), 256, 0, stream>>>(feats, Wc, bc, wsH);
  // sem (no relu) + out_cf (relu) merged: N = 50 + 512
  gemm4<false,true><<<dim3(36, 16), 256, 0, stream>>>(
      wsH, 512, Wsem, Wc2, 512, 50, bsem, bc2,
      out_sem, out_cf, 50, 512, 562, 512);
}

// Round 6
// 178.506 us; speedup vs baseline: 1.7033x; 1.7033x over previous
//
#include <hip/hip_runtime.h>
#include <stdint.h>

typedef unsigned short u16;
typedef __bf16 bf16x8 __attribute__((ext_vector_type(8)));
typedef float f32x4 __attribute__((ext_vector_type(4)));

#define DEVINL __device__ __forceinline__

DEVINL u16 f2bf(float f){
  uint32_t x = __float_as_uint(f);
  uint32_t r = (x + 0x7fffu + ((x >> 16) & 1u)) >> 16;
  return (u16)r;
}

DEVINL float wave_sum(float v){
#pragma unroll
  for (int off = 32; off; off >>= 1) v += __shfl_xor(v, off);
  return v;
}

DEVINL float dot8(float4 a0, float4 a1, float4 b0, float4 b1){
  return a0.x*b0.x + a0.y*b0.y + a0.z*b0.z + a0.w*b0.w
       + a1.x*b1.x + a1.y*b1.y + a1.z*b1.z + a1.w*b1.w;
}

DEVINL void gload_lds16(const void* g, void* l){
  __builtin_amdgcn_global_load_lds(
      (const __attribute__((address_space(1))) uint32_t*)g,
      (__attribute__((address_space(3))) uint32_t*)l, 16, 0, 0);
}

// ---------------- fused: cf = relu(Wp @ pf + bp)  +  wconv + flag init ------
__global__ __launch_bounds__(256) void cfw_kernel(
    const float* __restrict__ Wp, const float* __restrict__ pf,
    const float* __restrict__ bp, const float* __restrict__ Wop,
    float* __restrict__ feats, u16* __restrict__ wfb, int* __restrict__ flag)
{
  const int bid = blockIdx.x, tid = threadIdx.x;
  if (bid == 0 && tid == 0) *flag = 0;
  if (bid < 16384){
    const int lane = tid & 63, wid = tid >> 6;
    const int n = (bid << 2) + wid;                 // 0..65535
    const float4* row = (const float4*)(Wp + (size_t)n * 512);
    const float4* p   = (const float4*)pf;
    float4 w0 = row[lane*2], w1 = row[lane*2+1];
    float4 p0 = p[lane*2],  p1 = p[lane*2+1];
    float v = wave_sum(dot8(w0, w1, p0, p1));
    if (lane == 0){
      float r = fmaxf(v + bp[n], 0.f);
      feats[(size_t)(n >> 9) * 1536 + (n & 511)] = r;
    }
  } else {
    const int t = (bid - 16384) * 256 + tid;        // 0..65535
    const int e = t * 8;                            // elem in [2][512][512]
    const int it = e >> 18;
    const int rem = e & 262143;
    const int h = rem >> 9, k = rem & 511;
    const float* src = Wop + (size_t)it*788480 + (size_t)h*1540 + 1024 + k;
    float4 v0 = ((const float4*)src)[0];
    float4 v1 = ((const float4*)src)[1];
    union { u16 u[8]; uint4 q4; } o;
    o.u[0]=f2bf(v0.x); o.u[1]=f2bf(v0.y); o.u[2]=f2bf(v0.z); o.u[3]=f2bf(v0.w);
    o.u[4]=f2bf(v1.x); o.u[5]=f2bf(v1.y); o.u[6]=f2bf(v1.z); o.u[7]=f2bf(v1.w);
    *(uint4*)(wfb + e) = o.q4;
  }
}

// ---------------- 8 m-rows x 4 n-cols dot-GEMM unit (R4-proven) -------------
DEVINL void gemm_unit(const float* __restrict__ A, int lda,
                      const float* __restrict__ W, int ldw,
                      const float* __restrict__ bias,
                      float* __restrict__ C, int ldc,
                      int m0, int n0, int nmax, int K, bool relu, int lane)
{
  const float* wrow[4];
#pragma unroll
  for (int q = 0; q < 4; q++){
    int n = n0 + q; if (n >= nmax) n = nmax - 1;
    wrow[q] = W + (size_t)n * ldw + lane * 4;
  }
  const float* arow = A + (size_t)m0 * lda + lane * 4;
  float acc[8][4] = {};
  for (int kc = 0; kc < K; kc += 256){
    float4 w4[4];
#pragma unroll
    for (int q = 0; q < 4; q++) w4[q] = *(const float4*)(wrow[q] + kc);
#pragma unroll
    for (int r = 0; r < 8; r++){
      float4 a4 = *(const float4*)(arow + (size_t)r * lda + kc);
#pragma unroll
      for (int q = 0; q < 4; q++)
        acc[r][q] = fmaf(w4[q].x, a4.x, fmaf(w4[q].y, a4.y,
                    fmaf(w4[q].z, a4.z, fmaf(w4[q].w, a4.w, acc[r][q]))));
    }
  }
#pragma unroll
  for (int r = 0; r < 8; r++){
#pragma unroll
    for (int q = 0; q < 4; q++){
      float v = wave_sum(acc[r][q]);
      const int n = n0 + q;
      if (lane == 0 && n < nmax){
        float o = v + (bias ? bias[n] : 0.f);
        if (relu) o = fmaxf(o, 0.f);
        C[(size_t)(m0 + r) * ldc + n] = o;
      }
    }
  }
}

// ---------------- P/Q + it0 A/B (4 slabs, shared A=cf) + exists -------------
__global__ __launch_bounds__(256) void gemmPQAB(
    const float* __restrict__ feats,
    const float* __restrict__ Wel, const float* __restrict__ bel,
    const float* __restrict__ Wop, const float* __restrict__ bop,
    const float* __restrict__ We,  const float* __restrict__ be,
    float* __restrict__ P, float* __restrict__ Q,
    float* __restrict__ wsA, float* __restrict__ wsB,
    float* __restrict__ out_ex, float* __restrict__ exw)
{
  const int lane = threadIdx.x & 63, wid = threadIdx.x >> 6;
  const int bx = blockIdx.x, m0 = blockIdx.y * 8;
  if (bx < 128){
    const int n0 = (bx*4 + wid)*4;
    const int slab = n0 >> 9, nl = n0 & 511;
    const float* W; int ldw; const float* bias; float* C;
    switch (slab){
      case 0:  W = Wel;       ldw = 1024; bias = bel; C = P;   break;
      case 1:  W = Wel + 512; ldw = 1024; bias = 0;   C = Q;   break;
      case 2:  W = Wop;       ldw = 1540; bias = bop; C = wsA; break;
      default: W = Wop + 512; ldw = 1540; bias = 0;   C = wsB; break;
    }
    gemm_unit(feats, 1536, W, ldw, bias, C, 512, m0, nl, 512, 512, false, lane);
  } else {
    const float4* w = (const float4*)We;
    float4 w0 = w[lane*2], w1 = w[lane*2+1];
#pragma unroll
    for (int r = 0; r < 2; r++){
      const int m = m0 + wid*2 + r;
      const float4* a = (const float4*)(feats + (size_t)m*1536);
      float v = wave_sum(dot8(a[lane*2], a[lane*2+1], w0, w1));
      if (lane == 0){ float o = v + be[0]; out_ex[m] = o; exw[m] = o; }
    }
  }
}

// ---------------- el (bf16) + eel (f32) + has_edges; one wave per (i,j) ------
__global__ __launch_bounds__(256) void el_kernel(
    const float* __restrict__ P, const float* __restrict__ Q,
    const float* __restrict__ Wee, const float* __restrict__ bee,
    const float* __restrict__ ex,
    u16* __restrict__ elb, float* __restrict__ eelOut, int* __restrict__ flag)
{
  const int lane = threadIdx.x & 63, wid = threadIdx.x >> 6;
  const int row = (blockIdx.x << 2) + wid;          // 0..16383
  const int i = row >> 7, j = row & 127;
  const int k0 = lane << 3;
  float4 p0 = *(const float4*)(P + (size_t)i*512 + k0);
  float4 p1 = *(const float4*)(P + (size_t)i*512 + k0 + 4);
  float4 q0 = *(const float4*)(Q + (size_t)j*512 + k0);
  float4 q1 = *(const float4*)(Q + (size_t)j*512 + k0 + 4);
  float e[8];
  e[0]=fmaxf(p0.x+q0.x,0.f); e[1]=fmaxf(p0.y+q0.y,0.f);
  e[2]=fmaxf(p0.z+q0.z,0.f); e[3]=fmaxf(p0.w+q0.w,0.f);
  e[4]=fmaxf(p1.x+q1.x,0.f); e[5]=fmaxf(p1.y+q1.y,0.f);
  e[6]=fmaxf(p1.z+q1.z,0.f); e[7]=fmaxf(p1.w+q1.w,0.f);
  union { u16 u[8]; uint4 q4; } o;
#pragma unroll
  for (int c = 0; c < 8; c++) o.u[c] = f2bf(e[c]);
  *(uint4*)(elb + (size_t)row*512 + k0) = o.q4;
  float acc[4];
#pragma unroll
  for (int t = 0; t < 4; t++){
    float4 w0 = *(const float4*)(Wee + t*512 + k0);
    float4 w1 = *(const float4*)(Wee + t*512 + k0 + 4);
    acc[t] = wave_sum(e[0]*w0.x + e[1]*w0.y + e[2]*w0.z + e[3]*w0.w
                    + e[4]*w1.x + e[5]*w1.y + e[6]*w1.z + e[7]*w1.w);
  }
  bool wf = false;
  if (lane == 0){
    float4 r = make_float4(acc[0]+bee[0], acc[1]+bee[1], acc[2]+bee[2], acc[3]+bee[3]);
    *(float4*)(eelOut + (size_t)row*4) = r;
    wf = (ex[i] > 0.f) && (ex[j] > 0.f) &&
         (r.x > 0.f || r.y > 0.f || r.z > 0.f || r.w > 0.f);
  }
  // flag: ballot + load-guard -> at most a handful of actual atomics
  if (__ballot(wf)){
    if (lane == 0 &&
        __hip_atomic_load(flag, __ATOMIC_RELAXED, __HIP_MEMORY_SCOPE_AGENT) == 0)
      atomicOr(flag, 1);
  }
}

// ---------------- fused E-GEMM + msg + masked max per iteration -------------
// 1024 blocks: tile 128j x 64h, BK=64, dbuf, counted vmcnt(6) pipeline.
// XCD map: bid&7 = xcd; each XCD owns 16 i-panels x 8 h-tiles (L2 reuse).
__global__ __launch_bounds__(256, 3) void iter_kernel(
    const u16* __restrict__ el, const u16* __restrict__ wfb,
    const float* __restrict__ Aterm, const float* __restrict__ Bterm,
    const float* __restrict__ eel, const float* __restrict__ ex,
    const float* __restrict__ wopWt,      // Wop + it*788480 (Wt cols 1536..)
    const int* __restrict__ flag,
    float* __restrict__ feats, int it)
{
  __shared__ u16 tile[2][12288];    // per buf: A 128x64 bf16 (16KB) + B 64x64 (8KB)
  __shared__ float smax[4][64];
  const int tid = threadIdx.x;
  const int lane = tid & 63, wid = tid >> 6;
  const int bid = blockIdx.x;
  const int xcd = bid & 7, loc = bid >> 3;
  const int i   = xcd*16 + (loc & 15);
  const int hc0 = (loc >> 4) << 6;

  // staging: 6 chunks/thread/step (A:4, B:2), 16B each; LDS linear,
  // global col-slot pre-swizzled: cb = s ^ (r&7)  (8 slots of 16B per 128B row).
  const u16* src[6]; int dst[6];
#pragma unroll
  for (int rd = 0; rd < 6; rd++){
    int c = tid + 256*rd;
    if (c < 1024){
      int r = c >> 3, s = c & 7, cb = s ^ (r & 7);
      src[rd] = el + (size_t)(i*128 + r)*512 + (cb << 3);
      dst[rd] = c << 3;
    } else {
      int c2 = c - 1024;
      int r = c2 >> 3, s = c2 & 7, cb = s ^ (r & 7);
      src[rd] = wfb + (size_t)(hc0 + r)*512 + (cb << 3);
      dst[rd] = 8192 + (c2 << 3);
    }
  }

  const int slog = lane >> 4;
  int byteA[2][2], byteB[2][4];
#pragma unroll
  for (int k2 = 0; k2 < 2; k2++){
#pragma unroll
    for (int fa = 0; fa < 2; fa++){
      int ra = wid*32 + fa*16 + (lane & 15);
      byteA[k2][fa] = ra*128 + (((k2*4 + slog) ^ (ra & 7)) << 4);
    }
#pragma unroll
    for (int f = 0; f < 4; f++){
      int rb = f*16 + (lane & 15);
      byteB[k2][f] = 16384 + rb*128 + (((k2*4 + slog) ^ (rb & 7)) << 4);
    }
  }

  f32x4 acc[2][4] = {};

  auto stage = [&](int buf, int ks){
    const int k0 = ks << 6;
#pragma unroll
    for (int rd = 0; rd < 6; rd++)
      gload_lds16(src[rd] + k0, &tile[buf][dst[rd]]);
  };

  // counted-vmcnt double-buffer pipeline: batch k+2 in flight during compute k
  stage(0, 0);
  stage(1, 1);
  asm volatile("s_waitcnt vmcnt(6)" ::: "memory");   // batch0 landed
  __builtin_amdgcn_s_barrier();
  __builtin_amdgcn_sched_barrier(0);
#pragma unroll
  for (int ks = 0; ks < 8; ks++){
    const int cur = ks & 1;
    const char* base = (const char*)&tile[cur][0];
#pragma unroll
    for (int k2 = 0; k2 < 2; k2++){
      bf16x8 a[2], b[4];
#pragma unroll
      for (int fa = 0; fa < 2; fa++) a[fa] = *(const bf16x8*)(base + byteA[k2][fa]);
#pragma unroll
      for (int f = 0; f < 4; f++)   b[f]  = *(const bf16x8*)(base + byteB[k2][f]);
#pragma unroll
      for (int fa = 0; fa < 2; fa++)
#pragma unroll
        for (int f = 0; f < 4; f++)
          acc[fa][f] = __builtin_amdgcn_mfma_f32_16x16x32_bf16(a[fa], b[f], acc[fa][f], 0, 0, 0);
    }
    __builtin_amdgcn_s_barrier();      // all waves done reading tile[cur]
    __builtin_amdgcn_sched_barrier(0);
    if (ks < 6){
      stage(cur, ks + 2);              // overwrite cur with batch ks+2
      asm volatile("s_waitcnt vmcnt(6)" ::: "memory");  // batch ks+1 landed
    } else {
      asm volatile("s_waitcnt vmcnt(0)" ::: "memory");  // tail drain
    }
    __builtin_amdgcn_s_barrier();
    __builtin_amdgcn_sched_barrier(0);
  }

  // epilogue: msg = relu(pre + e0*Wt), masked max over (j,t)
  const bool mi = ex[i] > 0.f;
  float Ah[4]; float4 wt[4]; int hg[4];
#pragma unroll
  for (int f = 0; f < 4; f++){
    hg[f] = hc0 + f*16 + (lane & 15);
    Ah[f] = Aterm[i*512 + hg[f]];
    wt[f] = *(const float4*)(wopWt + (size_t)hg[f]*1540 + 1536);
  }
  float tm[4] = {0.f, 0.f, 0.f, 0.f};
#pragma unroll
  for (int fa = 0; fa < 2; fa++){
    const int j0 = wid*32 + fa*16 + slog*4;
#pragma unroll
    for (int r = 0; r < 4; r++){
      const int j = j0 + r;
      float4 e4 = *(const float4*)(eel + (size_t)(i*128 + j)*4);
      const bool mj = mi && (ex[j] > 0.f);
      const bool c0 = mj && (e4.x > 0.f), c1 = mj && (e4.y > 0.f);
      const bool c2 = mj && (e4.z > 0.f), c3 = mj && (e4.w > 0.f);
#pragma unroll
      for (int f = 0; f < 4; f++){
        float val = acc[fa][f][r] + Ah[f] + Bterm[(size_t)j*512 + hg[f]];
        if (c0) tm[f] = fmaxf(tm[f], val + e4.x*wt[f].x);
        if (c1) tm[f] = fmaxf(tm[f], val + e4.y*wt[f].y);
        if (c2) tm[f] = fmaxf(tm[f], val + e4.z*wt[f].z);
        if (c3) tm[f] = fmaxf(tm[f], val + e4.w*wt[f].w);
      }
    }
  }
#pragma unroll
  for (int f = 0; f < 4; f++){
    float v = tm[f];
    v = fmaxf(v, __shfl_xor(v, 16));
    v = fmaxf(v, __shfl_xor(v, 32));
    if (lane < 16) smax[wid][f*16 + lane] = v;
  }
  __syncthreads();
  if (tid < 64){
    const float v = fmaxf(fmaxf(smax[0][tid], smax[1][tid]),
                          fmaxf(smax[2][tid], smax[3][tid]));
    const int hgl = hc0 + tid;
    const float prev = feats[(size_t)i*1536 + it*512 + hgl];
    feats[(size_t)i*1536 + 512 + it*512 + hgl] = (*flag) ? v : prev;
  }
}

// ---------------- gemm4: dual slab, per-slab relu/ldc ------------------------
template<bool RA, bool RB>
__global__ __launch_bounds__(256) void gemm4(
    const float* __restrict__ A, int lda,
    const float* __restrict__ Wa, const float* __restrict__ Wb,
    int ldw, int Nsplit,
    const float* __restrict__ biasA, const float* __restrict__ biasB,
    float* __restrict__ Ca, float* __restrict__ Cb, int ldcA, int ldcB,
    int N, int K)
{
  const int lane = threadIdx.x & 63, wid = threadIdx.x >> 6;
  const int n0 = (blockIdx.x * 4 + wid) * 4;
  const int m0 = blockIdx.y * 8;
  const float* wrow[4];
#pragma unroll
  for (int q = 0; q < 4; q++){
    int n = n0 + q;
    int nn = n; const float* W = Wa;
    if (n >= Nsplit){ nn = n - Nsplit; W = Wb; }
    if (n >= N){ nn = 0; W = Wa; }
    wrow[q] = W + (size_t)nn * ldw + lane * 4;
  }
  const float* arow = A + (size_t)m0 * lda + lane * 4;
  float acc[8][4] = {};
  for (int kc = 0; kc < K; kc += 256){
    float4 w4[4];
#pragma unroll
    for (int q = 0; q < 4; q++) w4[q] = *(const float4*)(wrow[q] + kc);
#pragma unroll
    for (int r = 0; r < 8; r++){
      float4 a4 = *(const float4*)(arow + (size_t)r * lda + kc);
#pragma unroll
      for (int q = 0; q < 4; q++)
        acc[r][q] = fmaf(w4[q].x, a4.x, fmaf(w4[q].y, a4.y,
                    fmaf(w4[q].z, a4.z, fmaf(w4[q].w, a4.w, acc[r][q]))));
    }
  }
#pragma unroll
  for (int r = 0; r < 8; r++){
#pragma unroll
    for (int q = 0; q < 4; q++){
      float v = wave_sum(acc[r][q]);
      const int n = n0 + q;
      if (lane == 0 && n < N){
        const bool sb = n >= Nsplit;
        const float* bs = sb ? biasB : biasA;
        float o = v + (bs ? bs[sb ? n - Nsplit : n] : 0.f);
        if (sb ? RB : RA) o = fmaxf(o, 0.f);
        if (sb) Cb[(size_t)(m0 + r) * ldcB + (n - Nsplit)] = o;
        else    Ca[(size_t)(m0 + r) * ldcA + n] = o;
      }
    }
  }
}

// ---------------------------------------------------------------------------
extern "C" void kernel_launch(void* const* d_in, const int* in_sizes, int n_in,
                              void* d_out, int out_size, void* d_ws, size_t ws_size,
                              hipStream_t stream)
{
  const float* pf   = (const float*)d_in[0];
  const float* Wp   = (const float*)d_in[1];
  const float* bp   = (const float*)d_in[2];
  const float* We   = (const float*)d_in[3];
  const float* be   = (const float*)d_in[4];
  const float* Wsem = (const float*)d_in[5];
  const float* bsem = (const float*)d_in[6];
  const float* Wel  = (const float*)d_in[7];
  const float* bel  = (const float*)d_in[8];
  const float* Wee  = (const float*)d_in[9];
  const float* bee  = (const float*)d_in[10];
  const float* Wop  = (const float*)d_in[11];
  const float* bop  = (const float*)d_in[12];
  const float* Wc   = (const float*)d_in[13];
  const float* bc   = (const float*)d_in[14];
  const float* Wc2  = (const float*)d_in[15];
  const float* bc2  = (const float*)d_in[16];

  float* out      = (float*)d_out;
  float* out_cf   = out;             // [128,512]
  float* out_sem  = out + 65536;     // [128,50]
  float* out_ex   = out + 71936;     // [128]
  float* out_eel  = out + 72064;     // [128,128,4]

  char* ws = (char*)d_ws;
  u16*   elb   = (u16*)ws;                                // 16 MB bf16 el
  float* feats = (float*)(ws + 16777216);                 // [128][1536]
  float* P     = feats + 196608;                          // [128][512]
  float* Q     = P + 65536;
  float* wsA   = Q + 65536;
  float* wsB   = wsA + 65536;
  float* wsH   = wsB + 65536;
  float* exw   = wsH + 65536;                             // [128]
  int*   flag  = (int*)(exw + 160);
  u16*   wfb   = (u16*)(flag + 64);                       // [2][512][512] bf16

  cfw_kernel<<<16640, 256, 0, stream>>>(Wp, pf, bp, Wop, feats, wfb, flag);
  gemmPQAB<<<dim3(129, 16), 256, 0, stream>>>(feats, Wel, bel, Wop, bop, We, be,
                                              P, Q, wsA, wsB, out_ex, exw);
  el_kernel<<<4096, 256, 0, stream>>>(P, Q, Wee, bee, exw, elb, out_eel, flag);

  for (int it = 0; it < 2; it++){
    const float* Wit = Wop + (size_t)it * 788480;
    if (it == 1)
      gemm4<false,false><<<dim3(64, 16), 256, 0, stream>>>(
          feats + 512, 1536, Wit, Wit + 512, 1540, 512,
          bop + 512, nullptr, wsA, wsB, 512, 512, 1024, 512);
    iter_kernel<<<1024, 256, 0, stream>>>(elb, wfb + it*262144, wsA, wsB,
                                          out_eel, exw, Wit, flag, feats, it);
  }
  // head: h = relu(feats @ Wc.T + bc)
  gemm4<true,true><<<dim3(32, 16), 256, 0, stream>>>(
      feats, 1536, Wc, Wc, 1536, 512, bc, nullptr,
      wsH, wsH, 512, 512, 512, 1536);
  // sem (no relu) + out_cf (relu) merged: N = 50 + 512
  gemm4<false,true><<<dim3(36, 16), 256, 0, stream>>>(
      wsH, 512, Wsem, Wc2, 512, 50, bsem, bc2,
      out_sem, out_cf, 50, 512, 562, 512);
}

// Round 7
// 161.704 us; speedup vs baseline: 1.8803x; 1.1039x over previous
//
#include <hip/hip_runtime.h>
#include <stdint.h>

typedef unsigned short u16;
typedef __bf16 bf16x8 __attribute__((ext_vector_type(8)));
typedef float f32x4 __attribute__((ext_vector_type(4)));

#define DEVINL __device__ __forceinline__

DEVINL u16 f2bf(float f){
  uint32_t x = __float_as_uint(f);
  uint32_t r = (x + 0x7fffu + ((x >> 16) & 1u)) >> 16;
  return (u16)r;
}

DEVINL float wave_sum(float v){
#pragma unroll
  for (int off = 32; off; off >>= 1) v += __shfl_xor(v, off);
  return v;
}

DEVINL float dot8(float4 a0, float4 a1, float4 b0, float4 b1){
  return a0.x*b0.x + a0.y*b0.y + a0.z*b0.z + a0.w*b0.w
       + a1.x*b1.x + a1.y*b1.y + a1.z*b1.z + a1.w*b1.w;
}

DEVINL void gload_lds16(const void* g, void* l){
  __builtin_amdgcn_global_load_lds(
      (const __attribute__((address_space(1))) uint32_t*)g,
      (__attribute__((address_space(3))) uint32_t*)l, 16, 0, 0);
}

// ---------------- fused: cf = relu(Wp @ pf + bp)  +  wconv + flag init ------
__global__ __launch_bounds__(256) void cfw_kernel(
    const float* __restrict__ Wp, const float* __restrict__ pf,
    const float* __restrict__ bp, const float* __restrict__ Wop,
    float* __restrict__ feats, u16* __restrict__ wfb, int* __restrict__ flag)
{
  const int bid = blockIdx.x, tid = threadIdx.x;
  if (bid == 0 && tid == 0) *flag = 0;
  if (bid < 16384){
    const int lane = tid & 63, wid = tid >> 6;
    const int n = (bid << 2) + wid;                 // 0..65535
    const float4* row = (const float4*)(Wp + (size_t)n * 512);
    const float4* p   = (const float4*)pf;
    float4 w0 = row[lane*2], w1 = row[lane*2+1];
    float4 p0 = p[lane*2],  p1 = p[lane*2+1];
    float v = wave_sum(dot8(w0, w1, p0, p1));
    if (lane == 0){
      float r = fmaxf(v + bp[n], 0.f);
      feats[(size_t)(n >> 9) * 1536 + (n & 511)] = r;
    }
  } else {
    const int t = (bid - 16384) * 256 + tid;        // 0..65535
    const int e = t * 8;                            // elem in [2][512][512]
    const int it = e >> 18;
    const int rem = e & 262143;
    const int h = rem >> 9, k = rem & 511;
    const float* src = Wop + (size_t)it*788480 + (size_t)h*1540 + 1024 + k;
    float4 v0 = ((const float4*)src)[0];
    float4 v1 = ((const float4*)src)[1];
    union { u16 u[8]; uint4 q4; } o;
    o.u[0]=f2bf(v0.x); o.u[1]=f2bf(v0.y); o.u[2]=f2bf(v0.z); o.u[3]=f2bf(v0.w);
    o.u[4]=f2bf(v1.x); o.u[5]=f2bf(v1.y); o.u[6]=f2bf(v1.z); o.u[7]=f2bf(v1.w);
    *(uint4*)(wfb + e) = o.q4;
  }
}

// ---------------- 8 m-rows x 4 n-cols dot-GEMM unit (R4-proven) -------------
DEVINL void gemm_unit(const float* __restrict__ A, int lda,
                      const float* __restrict__ W, int ldw,
                      const float* __restrict__ bias,
                      float* __restrict__ C, int ldc,
                      int m0, int n0, int nmax, int K, bool relu, int lane)
{
  const float* wrow[4];
#pragma unroll
  for (int q = 0; q < 4; q++){
    int n = n0 + q; if (n >= nmax) n = nmax - 1;
    wrow[q] = W + (size_t)n * ldw + lane * 4;
  }
  const float* arow = A + (size_t)m0 * lda + lane * 4;
  float acc[8][4] = {};
  for (int kc = 0; kc < K; kc += 256){
    float4 w4[4];
#pragma unroll
    for (int q = 0; q < 4; q++) w4[q] = *(const float4*)(wrow[q] + kc);
#pragma unroll
    for (int r = 0; r < 8; r++){
      float4 a4 = *(const float4*)(arow + (size_t)r * lda + kc);
#pragma unroll
      for (int q = 0; q < 4; q++)
        acc[r][q] = fmaf(w4[q].x, a4.x, fmaf(w4[q].y, a4.y,
                    fmaf(w4[q].z, a4.z, fmaf(w4[q].w, a4.w, acc[r][q]))));
    }
  }
#pragma unroll
  for (int r = 0; r < 8; r++){
#pragma unroll
    for (int q = 0; q < 4; q++){
      float v = wave_sum(acc[r][q]);
      const int n = n0 + q;
      if (lane == 0 && n < nmax){
        float o = v + (bias ? bias[n] : 0.f);
        if (relu) o = fmaxf(o, 0.f);
        C[(size_t)(m0 + r) * ldc + n] = o;
      }
    }
  }
}

// ---------------- P/Q + it0 A/B (4 slabs, shared A=cf) + exists -------------
__global__ __launch_bounds__(256) void gemmPQAB(
    const float* __restrict__ feats,
    const float* __restrict__ Wel, const float* __restrict__ bel,
    const float* __restrict__ Wop, const float* __restrict__ bop,
    const float* __restrict__ We,  const float* __restrict__ be,
    float* __restrict__ P, float* __restrict__ Q,
    float* __restrict__ wsA, float* __restrict__ wsB,
    float* __restrict__ out_ex, float* __restrict__ exw)
{
  const int lane = threadIdx.x & 63, wid = threadIdx.x >> 6;
  const int bx = blockIdx.x, m0 = blockIdx.y * 8;
  if (bx < 128){
    const int n0 = (bx*4 + wid)*4;
    const int slab = n0 >> 9, nl = n0 & 511;
    const float* W; int ldw; const float* bias; float* C;
    switch (slab){
      case 0:  W = Wel;       ldw = 1024; bias = bel; C = P;   break;
      case 1:  W = Wel + 512; ldw = 1024; bias = 0;   C = Q;   break;
      case 2:  W = Wop;       ldw = 1540; bias = bop; C = wsA; break;
      default: W = Wop + 512; ldw = 1540; bias = 0;   C = wsB; break;
    }
    gemm_unit(feats, 1536, W, ldw, bias, C, 512, m0, nl, 512, 512, false, lane);
  } else {
    const float4* w = (const float4*)We;
    float4 w0 = w[lane*2], w1 = w[lane*2+1];
#pragma unroll
    for (int r = 0; r < 2; r++){
      const int m = m0 + wid*2 + r;
      const float4* a = (const float4*)(feats + (size_t)m*1536);
      float v = wave_sum(dot8(a[lane*2], a[lane*2+1], w0, w1));
      if (lane == 0){ float o = v + be[0]; out_ex[m] = o; exw[m] = o; }
    }
  }
}

// ---------------- el (bf16) + eel + has_edges; one wave per j-PAIR ----------
__global__ __launch_bounds__(256) void el_kernel(
    const float* __restrict__ P, const float* __restrict__ Q,
    const float* __restrict__ Wee, const float* __restrict__ bee,
    const float* __restrict__ ex,
    u16* __restrict__ elb, float* __restrict__ eelOut, int* __restrict__ flag)
{
  const int lane = threadIdx.x & 63, wid = threadIdx.x >> 6;
  const int pr = (blockIdx.x << 2) + wid;           // 0..8191 pair index
  const int i = pr >> 6, j0 = (pr & 63) << 1;       // same i for j0, j0+1
  const int row0 = i*128 + j0;
  const int k0 = lane << 3;
  float4 p0 = *(const float4*)(P + (size_t)i*512 + k0);
  float4 p1 = *(const float4*)(P + (size_t)i*512 + k0 + 4);
  float4 qa0 = *(const float4*)(Q + (size_t)j0*512 + k0);
  float4 qa1 = *(const float4*)(Q + (size_t)j0*512 + k0 + 4);
  float4 qb0 = *(const float4*)(Q + (size_t)(j0+1)*512 + k0);
  float4 qb1 = *(const float4*)(Q + (size_t)(j0+1)*512 + k0 + 4);
  float ea[8], eb[8];
  ea[0]=fmaxf(p0.x+qa0.x,0.f); ea[1]=fmaxf(p0.y+qa0.y,0.f);
  ea[2]=fmaxf(p0.z+qa0.z,0.f); ea[3]=fmaxf(p0.w+qa0.w,0.f);
  ea[4]=fmaxf(p1.x+qa1.x,0.f); ea[5]=fmaxf(p1.y+qa1.y,0.f);
  ea[6]=fmaxf(p1.z+qa1.z,0.f); ea[7]=fmaxf(p1.w+qa1.w,0.f);
  eb[0]=fmaxf(p0.x+qb0.x,0.f); eb[1]=fmaxf(p0.y+qb0.y,0.f);
  eb[2]=fmaxf(p0.z+qb0.z,0.f); eb[3]=fmaxf(p0.w+qb0.w,0.f);
  eb[4]=fmaxf(p1.x+qb1.x,0.f); eb[5]=fmaxf(p1.y+qb1.y,0.f);
  eb[6]=fmaxf(p1.z+qb1.z,0.f); eb[7]=fmaxf(p1.w+qb1.w,0.f);
  union { u16 u[8]; uint4 q4; } oa, ob;
#pragma unroll
  for (int c = 0; c < 8; c++){ oa.u[c] = f2bf(ea[c]); ob.u[c] = f2bf(eb[c]); }
  *(uint4*)(elb + (size_t)row0*512 + k0) = oa.q4;
  *(uint4*)(elb + (size_t)(row0+1)*512 + k0) = ob.q4;
  float acca[4], accb[4];
#pragma unroll
  for (int t = 0; t < 4; t++){
    float4 w0 = *(const float4*)(Wee + t*512 + k0);
    float4 w1 = *(const float4*)(Wee + t*512 + k0 + 4);
    acca[t] = wave_sum(ea[0]*w0.x + ea[1]*w0.y + ea[2]*w0.z + ea[3]*w0.w
                     + ea[4]*w1.x + ea[5]*w1.y + ea[6]*w1.z + ea[7]*w1.w);
    accb[t] = wave_sum(eb[0]*w0.x + eb[1]*w0.y + eb[2]*w0.z + eb[3]*w0.w
                     + eb[4]*w1.x + eb[5]*w1.y + eb[6]*w1.z + eb[7]*w1.w);
  }
  bool wf = false;
  if (lane == 0){
    float4 ra = make_float4(acca[0]+bee[0], acca[1]+bee[1], acca[2]+bee[2], acca[3]+bee[3]);
    float4 rb = make_float4(accb[0]+bee[0], accb[1]+bee[1], accb[2]+bee[2], accb[3]+bee[3]);
    *(float4*)(eelOut + (size_t)row0*4) = ra;
    *(float4*)(eelOut + (size_t)(row0+1)*4) = rb;
    const bool exi = ex[i] > 0.f;
    wf = (exi && (ex[j0] > 0.f) &&
          (ra.x > 0.f || ra.y > 0.f || ra.z > 0.f || ra.w > 0.f))
      || (exi && (ex[j0+1] > 0.f) &&
          (rb.x > 0.f || rb.y > 0.f || rb.z > 0.f || rb.w > 0.f));
  }
  // flag: ballot + load-guard -> at most a handful of actual atomics
  if (__ballot(wf)){
    if (lane == 0 &&
        __hip_atomic_load(flag, __ATOMIC_RELAXED, __HIP_MEMORY_SCOPE_AGENT) == 0)
      atomicOr(flag, 1);
  }
}

// ---------------- fused E-GEMM + msg + masked max per iteration -------------
// 1024 blocks: tile 128j x 64h, BK=64, dbuf, counted vmcnt(6) pipeline.
// XCD map: bid&7 = xcd; each XCD owns 16 i-panels x 8 h-tiles (L2 reuse).
__global__ __launch_bounds__(256, 3) void iter_kernel(
    const u16* __restrict__ el, const u16* __restrict__ wfb,
    const float* __restrict__ Aterm, const float* __restrict__ Bterm,
    const float* __restrict__ eel, const float* __restrict__ ex,
    const float* __restrict__ wopWt,      // Wop + it*788480 (Wt cols 1536..)
    const int* __restrict__ flag,
    float* __restrict__ feats, int it)
{
  __shared__ u16 tile[2][12288];    // per buf: A 128x64 bf16 (16KB) + B 64x64 (8KB)
  __shared__ float smax[4][64];
  const int tid = threadIdx.x;
  const int lane = tid & 63, wid = tid >> 6;
  const int bid = blockIdx.x;
  const int xcd = bid & 7, loc = bid >> 3;
  const int i   = xcd*16 + (loc & 15);
  const int hc0 = (loc >> 4) << 6;

  // staging: 6 chunks/thread/step (A:4, B:2), 16B each; LDS linear,
  // global col-slot pre-swizzled: cb = s ^ (r&7)  (8 slots of 16B per 128B row).
  const u16* src[6]; int dst[6];
#pragma unroll
  for (int rd = 0; rd < 6; rd++){
    int c = tid + 256*rd;
    if (c < 1024){
      int r = c >> 3, s = c & 7, cb = s ^ (r & 7);
      src[rd] = el + (size_t)(i*128 + r)*512 + (cb << 3);
      dst[rd] = c << 3;
    } else {
      int c2 = c - 1024;
      int r = c2 >> 3, s = c2 & 7, cb = s ^ (r & 7);
      src[rd] = wfb + (size_t)(hc0 + r)*512 + (cb << 3);
      dst[rd] = 8192 + (c2 << 3);
    }
  }

  const int slog = lane >> 4;
  int byteA[2][2], byteB[2][4];
#pragma unroll
  for (int k2 = 0; k2 < 2; k2++){
#pragma unroll
    for (int fa = 0; fa < 2; fa++){
      int ra = wid*32 + fa*16 + (lane & 15);
      byteA[k2][fa] = ra*128 + (((k2*4 + slog) ^ (ra & 7)) << 4);
    }
#pragma unroll
    for (int f = 0; f < 4; f++){
      int rb = f*16 + (lane & 15);
      byteB[k2][f] = 16384 + rb*128 + (((k2*4 + slog) ^ (rb & 7)) << 4);
    }
  }

  f32x4 acc[2][4] = {};

  auto stage = [&](int buf, int ks){
    const int k0 = ks << 6;
#pragma unroll
    for (int rd = 0; rd < 6; rd++)
      gload_lds16(src[rd] + k0, &tile[buf][dst[rd]]);
  };

  // counted-vmcnt double-buffer pipeline: batch k+2 in flight during compute k
  stage(0, 0);
  stage(1, 1);
  asm volatile("s_waitcnt vmcnt(6)" ::: "memory");   // batch0 landed
  __builtin_amdgcn_s_barrier();
  __builtin_amdgcn_sched_barrier(0);
#pragma unroll
  for (int ks = 0; ks < 8; ks++){
    const int cur = ks & 1;
    const char* base = (const char*)&tile[cur][0];
#pragma unroll
    for (int k2 = 0; k2 < 2; k2++){
      bf16x8 a[2], b[4];
#pragma unroll
      for (int fa = 0; fa < 2; fa++) a[fa] = *(const bf16x8*)(base + byteA[k2][fa]);
#pragma unroll
      for (int f = 0; f < 4; f++)   b[f]  = *(const bf16x8*)(base + byteB[k2][f]);
#pragma unroll
      for (int fa = 0; fa < 2; fa++)
#pragma unroll
        for (int f = 0; f < 4; f++)
          acc[fa][f] = __builtin_amdgcn_mfma_f32_16x16x32_bf16(a[fa], b[f], acc[fa][f], 0, 0, 0);
    }
    __builtin_amdgcn_s_barrier();      // all waves done reading tile[cur]
    __builtin_amdgcn_sched_barrier(0);
    if (ks < 6){
      stage(cur, ks + 2);              // overwrite cur with batch ks+2
      asm volatile("s_waitcnt vmcnt(6)" ::: "memory");  // batch ks+1 landed
    } else {
      asm volatile("s_waitcnt vmcnt(0)" ::: "memory");  // tail drain
    }
    __builtin_amdgcn_s_barrier();
    __builtin_amdgcn_sched_barrier(0);
  }

  // epilogue: msg = relu(pre + e0*Wt), masked max over (j,t)
  const bool mi = ex[i] > 0.f;
  float Ah[4]; float4 wt[4]; int hg[4];
#pragma unroll
  for (int f = 0; f < 4; f++){
    hg[f] = hc0 + f*16 + (lane & 15);
    Ah[f] = Aterm[i*512 + hg[f]];
    wt[f] = *(const float4*)(wopWt + (size_t)hg[f]*1540 + 1536);
  }
  float tm[4] = {0.f, 0.f, 0.f, 0.f};
#pragma unroll
  for (int fa = 0; fa < 2; fa++){
    const int j0 = wid*32 + fa*16 + slog*4;
#pragma unroll
    for (int r = 0; r < 4; r++){
      const int j = j0 + r;
      float4 e4 = *(const float4*)(eel + (size_t)(i*128 + j)*4);
      const bool mj = mi && (ex[j] > 0.f);
      const bool c0 = mj && (e4.x > 0.f), c1 = mj && (e4.y > 0.f);
      const bool c2 = mj && (e4.z > 0.f), c3 = mj && (e4.w > 0.f);
#pragma unroll
      for (int f = 0; f < 4; f++){
        float val = acc[fa][f][r] + Ah[f] + Bterm[(size_t)j*512 + hg[f]];
        if (c0) tm[f] = fmaxf(tm[f], val + e4.x*wt[f].x);
        if (c1) tm[f] = fmaxf(tm[f], val + e4.y*wt[f].y);
        if (c2) tm[f] = fmaxf(tm[f], val + e4.z*wt[f].z);
        if (c3) tm[f] = fmaxf(tm[f], val + e4.w*wt[f].w);
      }
    }
  }
#pragma unroll
  for (int f = 0; f < 4; f++){
    float v = tm[f];
    v = fmaxf(v, __shfl_xor(v, 16));
    v = fmaxf(v, __shfl_xor(v, 32));
    if (lane < 16) smax[wid][f*16 + lane] = v;
  }
  __syncthreads();
  if (tid < 64){
    const float v = fmaxf(fmaxf(smax[0][tid], smax[1][tid]),
                          fmaxf(smax[2][tid], smax[3][tid]));
    const int hgl = hc0 + tid;
    const float prev = feats[(size_t)i*1536 + it*512 + hgl];
    feats[(size_t)i*1536 + 512 + it*512 + hgl] = (*flag) ? v : prev;
  }
}

// ---------------- gemm4: dual slab, NC n-cols per wave ----------------------
template<bool RA, bool RB, int NC>
__global__ __launch_bounds__(256) void gemm4(
    const float* __restrict__ A, int lda,
    const float* __restrict__ Wa, const float* __restrict__ Wb,
    int ldw, int Nsplit,
    const float* __restrict__ biasA, const float* __restrict__ biasB,
    float* __restrict__ Ca, float* __restrict__ Cb, int ldcA, int ldcB,
    int N, int K)
{
  const int lane = threadIdx.x & 63, wid = threadIdx.x >> 6;
  const int n0 = (blockIdx.x * 4 + wid) * NC;
  const int m0 = blockIdx.y * 8;
  const float* wrow[NC];
#pragma unroll
  for (int q = 0; q < NC; q++){
    int n = n0 + q;
    int nn = n; const float* W = Wa;
    if (n >= Nsplit){ nn = n - Nsplit; W = Wb; }
    if (n >= N){ nn = 0; W = Wa; }
    wrow[q] = W + (size_t)nn * ldw + lane * 4;
  }
  const float* arow = A + (size_t)m0 * lda + lane * 4;
  float acc[8][NC] = {};
  for (int kc = 0; kc < K; kc += 256){
    float4 w4[NC];
#pragma unroll
    for (int q = 0; q < NC; q++) w4[q] = *(const float4*)(wrow[q] + kc);
#pragma unroll
    for (int r = 0; r < 8; r++){
      float4 a4 = *(const float4*)(arow + (size_t)r * lda + kc);
#pragma unroll
      for (int q = 0; q < NC; q++)
        acc[r][q] = fmaf(w4[q].x, a4.x, fmaf(w4[q].y, a4.y,
                    fmaf(w4[q].z, a4.z, fmaf(w4[q].w, a4.w, acc[r][q]))));
    }
  }
#pragma unroll
  for (int r = 0; r < 8; r++){
#pragma unroll
    for (int q = 0; q < NC; q++){
      float v = wave_sum(acc[r][q]);
      const int n = n0 + q;
      if (lane == 0 && n < N){
        const bool sb = n >= Nsplit;
        const float* bs = sb ? biasB : biasA;
        float o = v + (bs ? bs[sb ? n - Nsplit : n] : 0.f);
        if (sb ? RB : RA) o = fmaxf(o, 0.f);
        if (sb) Cb[(size_t)(m0 + r) * ldcB + (n - Nsplit)] = o;
        else    Ca[(size_t)(m0 + r) * ldcA + n] = o;
      }
    }
  }
}

// ---------------------------------------------------------------------------
extern "C" void kernel_launch(void* const* d_in, const int* in_sizes, int n_in,
                              void* d_out, int out_size, void* d_ws, size_t ws_size,
                              hipStream_t stream)
{
  const float* pf   = (const float*)d_in[0];
  const float* Wp   = (const float*)d_in[1];
  const float* bp   = (const float*)d_in[2];
  const float* We   = (const float*)d_in[3];
  const float* be   = (const float*)d_in[4];
  const float* Wsem = (const float*)d_in[5];
  const float* bsem = (const float*)d_in[6];
  const float* Wel  = (const float*)d_in[7];
  const float* bel  = (const float*)d_in[8];
  const float* Wee  = (const float*)d_in[9];
  const float* bee  = (const float*)d_in[10];
  const float* Wop  = (const float*)d_in[11];
  const float* bop  = (const float*)d_in[12];
  const float* Wc   = (const float*)d_in[13];
  const float* bc   = (const float*)d_in[14];
  const float* Wc2  = (const float*)d_in[15];
  const float* bc2  = (const float*)d_in[16];

  float* out      = (float*)d_out;
  float* out_cf   = out;             // [128,512]
  float* out_sem  = out + 65536;     // [128,50]
  float* out_ex   = out + 71936;     // [128]
  float* out_eel  = out + 72064;     // [128,128,4]

  char* ws = (char*)d_ws;
  u16*   elb   = (u16*)ws;                                // 16 MB bf16 el
  float* feats = (float*)(ws + 16777216);                 // [128][1536]
  float* P     = feats + 196608;                          // [128][512]
  float* Q     = P + 65536;
  float* wsA   = Q + 65536;
  float* wsB   = wsA + 65536;
  float* wsH   = wsB + 65536;
  float* exw   = wsH + 65536;                             // [128]
  int*   flag  = (int*)(exw + 160);
  u16*   wfb   = (u16*)(flag + 64);                       // [2][512][512] bf16

  cfw_kernel<<<16640, 256, 0, stream>>>(Wp, pf, bp, Wop, feats, wfb, flag);
  gemmPQAB<<<dim3(129, 16), 256, 0, stream>>>(feats, Wel, bel, Wop, bop, We, be,
                                              P, Q, wsA, wsB, out_ex, exw);
  el_kernel<<<2048, 256, 0, stream>>>(P, Q, Wee, bee, exw, elb, out_eel, flag);

  for (int it = 0; it < 2; it++){
    const float* Wit = Wop + (size_t)it * 788480;
    if (it == 1)
      gemm4<false,false,2><<<dim3(128, 16), 256, 0, stream>>>(
          feats + 512, 1536, Wit, Wit + 512, 1540, 512,
          bop + 512, nullptr, wsA, wsB, 512, 512, 1024, 512);
    iter_kernel<<<1024, 256, 0, stream>>>(elb, wfb + it*262144, wsA, wsB,
                                          out_eel, exw, Wit, flag, feats, it);
  }
  // head: h = relu(feats @ Wc.T + bc), K=1536
  gemm4<true,true,2><<<dim3(64, 16), 256, 0, stream>>>(
      feats, 1536, Wc, Wc, 1536, 512, bc, nullptr,
      wsH, wsH, 512, 512, 512, 1536);
  // sem (no relu) + out_cf (relu) merged: N = 50 + 512
  gemm4<false,true,2><<<dim3(71, 16), 256, 0, stream>>>(
      wsH, 512, Wsem, Wc2, 512, 50, bsem, bc2,
      out_sem, out_cf, 50, 512, 562, 512);
}